// Round 12
// baseline (445.738 us; speedup 1.0000x reference)
//
#include <hip/hip_runtime.h>
#include <hip/hip_bf16.h>
#include <cstdint>
#include <cstddef>

typedef __hip_bfloat16 bf16;
typedef __attribute__((ext_vector_type(8))) short short8;
typedef __attribute__((ext_vector_type(4))) short short4v;
typedef __attribute__((ext_vector_type(4))) float floatx4;
typedef unsigned long long u64;

#define DEVI static __device__ __forceinline__

DEVI void load_lds16(const void* g, void* l) {
  __builtin_amdgcn_global_load_lds((const __attribute__((address_space(1))) unsigned int*)g,
                                   (__attribute__((address_space(3))) unsigned int*)l, 16, 0, 0);
}
DEVI short8 ld8(const bf16* p) { return *(const short8*)p; }
DEVI floatx4 mfma16(short8 a, short8 b, floatx4 c) {
  return __builtin_amdgcn_mfma_f32_16x16x32_bf16(a, b, c, 0, 0, 0);
}
DEVI floatx4 mfma1k(short4v a, short4v b, floatx4 c) {
  return __builtin_amdgcn_mfma_f32_16x16x16bf16_1k(a, b, c, 0, 0, 0);
}
DEVI short bfb(float f) { bf16 h = __float2bfloat16(f); return __builtin_bit_cast(short, h); }
DEVI float fbf(short s) { bf16 h = __builtin_bit_cast(bf16, s); return __bfloat162float(h); }

// ---------------- fused prep: x->bf16 + adj bits + all 6 weight transposes ----------------
// Block budget: 4096 (x/adj) + 4096 (Wq,Wk,Wv,Wo) + 2048 (W1) + 2048 (W2) = 12288.
DEVI void tr_tile(const float* in, bf16* out, int R, int C, int bx, int by) {
  __shared__ float t[32][33];
  int c0 = bx * 32, r0 = by * 32;
  int tx = threadIdx.x & 31, ty = threadIdx.x >> 5;
#pragma unroll
  for (int i = 0; i < 32; i += 8) t[ty + i][tx] = in[(size_t)(r0 + ty + i) * C + c0 + tx];
  __syncthreads();
#pragma unroll
  for (int i = 0; i < 32; i += 8)
    out[(size_t)(c0 + ty + i) * R + r0 + tx] = __float2bfloat16(t[tx][ty + i]);
}

__global__ __launch_bounds__(256)
void prep_all(const float* __restrict__ x, bf16* __restrict__ xb,
              const float* __restrict__ adj, u64* __restrict__ bits,
              const float* Wq, const float* Wk, const float* Wv, const float* Wo,
              const float* W1, const float* W2,
              bf16* Wqkvt, bf16* Wot, bf16* W1t, bf16* W2t) {
  int id = blockIdx.x;
  if (id < 4096) {
    const int row = id, tid = threadIdx.x;
    const int wave = tid >> 6, lane = tid & 63;
    float4 v = ((const float4*)(x + (size_t)row * 1024))[tid];
    bf16* o = xb + (size_t)row * 1024 + tid * 4;
    o[0] = __float2bfloat16(v.x); o[1] = __float2bfloat16(v.y);
    o[2] = __float2bfloat16(v.z); o[3] = __float2bfloat16(v.w);
    const float* arow = adj + (size_t)row * 4096;
#pragma unroll
    for (int it = 0; it < 16; it++) {
      int col = it * 256 + tid;
      u64 m = __ballot(arow[col] != 0.f);
      if (lane == 0) bits[(size_t)row * 64 + it * 4 + wave] = m;
    }
  } else if (id < 8192) {
    int q = id - 4096, w = q >> 10, t = q & 1023;
    const float* in = w == 0 ? Wq : w == 1 ? Wk : w == 2 ? Wv : Wo;
    bf16* out = w == 0 ? Wqkvt : w == 1 ? Wqkvt + 1024ull * 1024
              : w == 2 ? Wqkvt + 2048ull * 1024 : Wot;
    tr_tile(in, out, 1024, 1024, t & 31, t >> 5);
  } else if (id < 10240) {
    int t = id - 8192;
    tr_tile(W1, W1t, 1024, 2048, t & 63, t >> 6);
  } else {
    int t = id - 10240;
    tr_tile(W2, W2t, 2048, 1024, t & 31, t >> 5);
  }
}

// ---------------- plain V^T build: out[dh][n] = V[n][dh] ----------------
__global__ __launch_bounds__(256)
void tr_bf16t(const bf16* __restrict__ in, bf16* __restrict__ out, int inLd) {
  __shared__ bf16 t[32][33];
  int c0 = blockIdx.x * 32, r0 = blockIdx.y * 32;
  int tx = threadIdx.x, ty = threadIdx.y;
#pragma unroll
  for (int i = 0; i < 32; i += 8) t[ty + i][tx] = in[(size_t)(r0 + ty + i) * inLd + c0 + tx];
  __syncthreads();
#pragma unroll
  for (int i = 0; i < 32; i += 8)
    out[(size_t)(c0 + ty + i) * 4096 + r0 + tx] = t[tx][ty + i];
}

// ---------------- bf16 GEMM, C = A[M][K] @ Bt[N][K]^T ----------------
// Pipelined K-loop: 3 LDS buffers, loads 2 tiles in flight, raw s_barrier with
// fine-grained vmcnt (never vmcnt(0) mid-loop).
// MODE 0: bf16 C (QKV) | MODE 2: bf16 gelu(C+bias) (FFN1)
// MODE 4: f32 partial; z==0 adds bias, z==1 adds resid (if non-null); K split by gridDim.z
template <int MODE>
__global__ __launch_bounds__(256)
void gemm_bt(const bf16* __restrict__ A, const bf16* __restrict__ Bt,
             const float* __restrict__ bias, const float* __restrict__ resid,
             float* __restrict__ outF, bf16* __restrict__ outB,
             int M, int Nn, int K) {
  __shared__ alignas(16) bf16 As[3][128 * 32];
  __shared__ alignas(16) bf16 Bs[3][128 * 32];
  const int tid = threadIdx.x;
  const int wave = tid >> 6, lane = tid & 63;
  const int m0 = blockIdx.y * 128, n0 = blockIdx.x * 128;
  const int wr = (wave >> 1) * 64, wc = (wave & 1) * 64;
  const int l15 = lane & 15, qq = lane >> 4;
  const int lr = lane >> 2, l4 = lane & 3;
  const int Kspan = K / gridDim.z;
  const int kbeg = blockIdx.z * Kspan;
  const int T = Kspan >> 5;

  floatx4 acc[4][4];
#pragma unroll
  for (int i = 0; i < 4; i++)
#pragma unroll
    for (int j = 0; j < 4; j++) acc[i][j] = (floatx4)0.f;

  const bf16* gA0 = A + (size_t)(m0 + wave * 16 + lr) * K + kbeg + l4 * 8;
  const bf16* gA1 = gA0 + (size_t)64 * K;
  const bf16* gB0 = Bt + (size_t)(n0 + wave * 16 + lr) * K + kbeg + l4 * 8;
  const bf16* gB1 = gB0 + (size_t)64 * K;
  const int lo = wave * 16 * 32;

  auto stage = [&](int t, int buf) {
    int kt = t * 32;
    load_lds16(gA0 + kt, &As[buf][lo]);
    load_lds16(gA1 + kt, &As[buf][64 * 32 + lo]);
    load_lds16(gB0 + kt, &Bs[buf][lo]);
    load_lds16(gB1 + kt, &Bs[buf][64 * 32 + lo]);
  };
  stage(0, 0);
  stage(1, 1);

  int bc = 0;
  for (int t = 0; t < T; ++t) {
    if (t < T - 1) asm volatile("s_waitcnt vmcnt(4) lgkmcnt(0)" ::: "memory");
    else           asm volatile("s_waitcnt vmcnt(0) lgkmcnt(0)" ::: "memory");
    __builtin_amdgcn_s_barrier();
    if (t + 2 < T) { int bs = bc == 0 ? 2 : bc - 1; stage(t + 2, bs); }

    short8 af[4], bfr[4];
#pragma unroll
    for (int mi = 0; mi < 4; mi++) af[mi] = ld8(&As[bc][(wr + mi * 16 + l15) * 32 + qq * 8]);
#pragma unroll
    for (int ni = 0; ni < 4; ni++) bfr[ni] = ld8(&Bs[bc][(wc + ni * 16 + l15) * 32 + qq * 8]);
#pragma unroll
    for (int mi = 0; mi < 4; mi++)
#pragma unroll
      for (int ni = 0; ni < 4; ni++)
        acc[mi][ni] = mfma16(af[mi], bfr[ni], acc[mi][ni]);
    bc = bc == 2 ? 0 : bc + 1;
  }

  const size_t zoff = (size_t)blockIdx.z * M * Nn;
#pragma unroll
  for (int mi = 0; mi < 4; mi++) {
    int row = m0 + wr + mi * 16 + qq * 4;
#pragma unroll
    for (int ni = 0; ni < 4; ni++) {
      int col = n0 + wc + ni * 16 + l15;
      float bv = 0.f;
      if (MODE == 2) bv = bias[col];
      if (MODE == 4 && blockIdx.z == 0) bv = bias[col];
#pragma unroll
      for (int r = 0; r < 4; r++) {
        float v = acc[mi][ni][r] + bv;
        size_t off = (size_t)(row + r) * Nn + col;
        if (MODE == 0) {
          outB[off] = __float2bfloat16(v);
        } else if (MODE == 2) {
          outB[off] = __float2bfloat16(0.5f * v * (1.f + erff(v * 0.70710678118654752f)));
        } else {
          if (resid && blockIdx.z == 1) v += resid[off];
          outF[zoff + off] = v;
        }
      }
    }
  }
}

// ---------------- flash attention v12: transposed-S + double-buffered async staging ------
// grid (32 q-tiles, 8 heads, 4 splits); 256 thr; LDS 64KB -> 2 blocks/CU.
// S^T = K·Q^T (C-layout = A-operand layout of 16x16x16 mfma) -> P stays in registers.
// 2-buffer staging with mid-loop s_waitcnt vmcnt(8) — staging never on critical path.
__global__ __launch_bounds__(256, 2)
void attn_kernel(const bf16* __restrict__ QKV, const bf16* __restrict__ Vt,
                 const u64* __restrict__ adjbits, const float* __restrict__ adj_bias,
                 bf16* __restrict__ AOpart, float* __restrict__ lpart) {
  __shared__ alignas(16) bf16 Kf[2][16 * 512];  // frag fi=ni*4+kk: K rows, 16KB per buf
  __shared__ alignas(16) bf16 Vf[2][16 * 512];  // frag fi=d*2+k2: V^T rows, 16KB per buf
  const int q0 = blockIdx.x * 128;
  const int h = blockIdx.y;
  const int split = blockIdx.z;
  const int k0 = split * 1024;
  const int tid = threadIdx.x, wave = tid >> 6, lane = tid & 63;
  const int l15 = lane & 15, qq = lane >> 4;
  const float beta = adj_bias[h];
  const float scale = 0.08838834764831845f;  // 128^-0.5

  // Q fragments (B-operand; 32 rows per wave)
  short8 qf[2][4];
#pragma unroll
  for (int mi = 0; mi < 2; mi++)
#pragma unroll
    for (int kk = 0; kk < 4; kk++)
      qf[mi][kk] = ld8(&QKV[(size_t)(q0 + wave * 32 + mi * 16 + l15) * 3072 +
                            h * 128 + kk * 32 + qq * 8]);

  floatx4 o[2][8];
#pragma unroll
  for (int mi = 0; mi < 2; mi++)
#pragma unroll
    for (int d = 0; d < 8; d++) o[mi][d] = (floatx4)0.f;
  float lrow[2] = {0.f, 0.f};

  const size_t abase = (size_t)(q0 + wave * 32 + l15) * 64 + split * 16;

  auto stage = [&](int t, int buf) {
    const int kt = k0 + t * 64;
#pragma unroll
    for (int i = 0; i < 4; i++) {
      int fi = wave * 4 + i;
      int ni = fi >> 2, kk = fi & 3;
      load_lds16(&QKV[(size_t)(kt + ni * 16 + l15) * 3072 + 1024 + h * 128 + kk * 32 + qq * 8],
                 (char*)Kf[buf] + fi * 1024);
      int d = fi >> 1, k2 = fi & 1;
      load_lds16(&Vt[(size_t)(h * 128 + d * 16 + l15) * 4096 + kt + k2 * 32 + qq * 8],
                 (char*)Vf[buf] + fi * 1024);
    }
  };

  u64 a0c = adjbits[abase + 0];
  u64 a1c = adjbits[abase + 1024 + 0];
  stage(0, 0);  // prologue: tile 0 in flight

  for (int t = 0; t < 16; t++) {
    const int buf = t & 1;
    __builtin_amdgcn_s_barrier();  // A: all waves done reading buf^1 (compute t-1)
    if (t < 15) {
      stage(t + 1, buf ^ 1);
      // own stage(t) (issued last iter) drained; stage(t+1)'s 8 newest stay in flight
      asm volatile("s_waitcnt vmcnt(8)" ::: "memory");
    } else {
      asm volatile("s_waitcnt vmcnt(0)" ::: "memory");
    }
    __builtin_amdgcn_s_barrier();  // B: tile t visible to all waves
    // adj prefetch for t+1 (issued after the asm barrier -> never in vmcnt window)
    u64 a0n = 0, a1n = 0;
    if (t < 15) { a0n = adjbits[abase + t + 1]; a1n = adjbits[abase + 1024 + t + 1]; }

    // per 16-key step: S^T -> softmax -> PV (P never touches LDS)
#pragma unroll
    for (int ni = 0; ni < 4; ni++) {
      floatx4 s0 = (floatx4)0.f, s1 = (floatx4)0.f;
#pragma unroll
      for (int kk = 0; kk < 4; kk++) {
        short8 kf = ld8(&Kf[buf][(ni * 4 + kk) * 512 + lane * 8]);
        s0 = mfma16(kf, qf[0][kk], s0);  // D[key][q] for q-subtile 0
        s1 = mfma16(kf, qf[1][kk], s1);
      }
      short4v pa0, pa1;
      {
        float p0, p1, p2, p3;
        int bp = ni * 16 + qq * 4;
        p0 = __expf(fmaf(s0[0], scale, ((a0c >> (bp + 0)) & 1) ? beta : 0.f));
        p1 = __expf(fmaf(s0[1], scale, ((a0c >> (bp + 1)) & 1) ? beta : 0.f));
        p2 = __expf(fmaf(s0[2], scale, ((a0c >> (bp + 2)) & 1) ? beta : 0.f));
        p3 = __expf(fmaf(s0[3], scale, ((a0c >> (bp + 3)) & 1) ? beta : 0.f));
        lrow[0] += (p0 + p1) + (p2 + p3);
        pa0.x = bfb(p0); pa0.y = bfb(p1); pa0.z = bfb(p2); pa0.w = bfb(p3);
        p0 = __expf(fmaf(s1[0], scale, ((a1c >> (bp + 0)) & 1) ? beta : 0.f));
        p1 = __expf(fmaf(s1[1], scale, ((a1c >> (bp + 1)) & 1) ? beta : 0.f));
        p2 = __expf(fmaf(s1[2], scale, ((a1c >> (bp + 2)) & 1) ? beta : 0.f));
        p3 = __expf(fmaf(s1[3], scale, ((a1c >> (bp + 3)) & 1) ? beta : 0.f));
        lrow[1] += (p0 + p1) + (p2 + p3);
        pa1.x = bfb(p0); pa1.y = bfb(p1); pa1.z = bfb(p2); pa1.w = bfb(p3);
      }
      // PV: B-frag = V^T[d*16+l15][kt+ni*16+qq*4 .. +3] from Vf (b64)
      const int voff = ((ni & 1) * 2 + (qq >> 1)) * 256 + l15 * 16 + (qq & 1) * 8;
#pragma unroll
      for (int d = 0; d < 8; d++) {
        short4v vf = *(const short4v*)((const char*)Vf[buf] + (d * 2 + (ni >> 1)) * 1024 + voff);
        o[0][d] = mfma1k(pa0, vf, o[0][d]);
        o[1][d] = mfma1k(pa1, vf, o[1][d]);
      }
    }
    a0c = a0n; a1c = a1n;
  }

  // epilogue: reduce lrow over quads; write bf16 partials (additive across splits)
#pragma unroll
  for (int mi = 0; mi < 2; mi++) {
    float v = lrow[mi];
    v += __shfl_xor(v, 16, 64);
    v += __shfl_xor(v, 32, 64);
    if (qq == 0) lpart[((size_t)split * 4096 + q0 + wave * 32 + mi * 16 + l15) * 8 + h] = v;
#pragma unroll
    for (int r = 0; r < 4; r++) {
      int grow = q0 + wave * 32 + mi * 16 + qq * 4 + r;
      bf16* dst = AOpart + ((size_t)split * 4096 + grow) * 1024 + h * 128;
#pragma unroll
      for (int d = 0; d < 8; d++) dst[d * 16 + l15] = __float2bfloat16(o[mi][d][r]);
    }
  }
}

// ---------------- combine split-K partials, normalize -> bf16 AO ----------------
__global__ __launch_bounds__(256)
void attn_norm(const bf16* __restrict__ AOpart, const float* __restrict__ lpart,
               bf16* __restrict__ AO) {
  int row = blockIdx.x, tid = threadIdx.x;
  int h = tid >> 5;
  float ls = 0.f;
#pragma unroll
  for (int s = 0; s < 4; s++) ls += lpart[((size_t)s * 4096 + row) * 8 + h];
  float a0 = 0.f, a1 = 0.f, a2 = 0.f, a3 = 0.f;
#pragma unroll
  for (int s = 0; s < 4; s++) {
    short4v v = *(const short4v*)&AOpart[((size_t)s * 4096 + row) * 1024 + tid * 4];
    a0 += fbf(v.x); a1 += fbf(v.y); a2 += fbf(v.z); a3 += fbf(v.w);
  }
  float inv = 1.f / ls;
  bf16* op = AO + (size_t)row * 1024 + tid * 4;
  op[0] = __float2bfloat16(a0 * inv);
  op[1] = __float2bfloat16(a1 * inv);
  op[2] = __float2bfloat16(a2 * inv);
  op[3] = __float2bfloat16(a3 * inv);
}

// ---------------- fused double-LayerNorm (two Wo partials) ----------------
DEVI void block_sum2(float& a, float& b, float* red) {
#pragma unroll
  for (int o = 1; o < 64; o <<= 1) { a += __shfl_xor(a, o, 64); b += __shfl_xor(b, o, 64); }
  int wv = threadIdx.x >> 6;
  if ((threadIdx.x & 63) == 0) { red[wv] = a; red[4 + wv] = b; }
  __syncthreads();
  a = red[0] + red[1] + red[2] + red[3];
  b = red[4] + red[5] + red[6] + red[7];
  __syncthreads();
}

__global__ __launch_bounds__(256)
void ln2_kernel(const float* __restrict__ x, const float* __restrict__ ao0,
                const float* __restrict__ ao1,
                const float* __restrict__ g1, const float* __restrict__ b1,
                const float* __restrict__ g2, const float* __restrict__ b2,
                float* __restrict__ hout, bf16* __restrict__ fln) {
  __shared__ float red[8];
  const int row = blockIdx.x, tid = threadIdx.x;
  float4 xv = ((const float4*)(x + (size_t)row * 1024))[tid];
  float4 av = ((const float4*)(ao0 + (size_t)row * 1024))[tid];
  float4 aw = ((const float4*)(ao1 + (size_t)row * 1024))[tid];
  float s0 = xv.x + av.x + aw.x, s1 = xv.y + av.y + aw.y;
  float s2 = xv.z + av.z + aw.z, s3 = xv.w + av.w + aw.w;
  float sum = s0 + s1 + s2 + s3;
  float ssq = s0 * s0 + s1 * s1 + s2 * s2 + s3 * s3;
  block_sum2(sum, ssq, red);
  float mu = sum * (1.f / 1024.f);
  float rs = rsqrtf(ssq * (1.f / 1024.f) - mu * mu + 1e-5f);
  float4 gv = ((const float4*)g1)[tid], bv = ((const float4*)b1)[tid];
  float h0 = (s0 - mu) * rs * gv.x + bv.x;
  float h1 = (s1 - mu) * rs * gv.y + bv.y;
  float h2 = (s2 - mu) * rs * gv.z + bv.z;
  float h3 = (s3 - mu) * rs * gv.w + bv.w;
  float4 hv; hv.x = h0; hv.y = h1; hv.z = h2; hv.w = h3;
  ((float4*)(hout + (size_t)row * 1024))[tid] = hv;
  float sum2 = h0 + h1 + h2 + h3;
  float ssq2 = h0 * h0 + h1 * h1 + h2 * h2 + h3 * h3;
  block_sum2(sum2, ssq2, red);
  float mu2 = sum2 * (1.f / 1024.f);
  float rs2 = rsqrtf(ssq2 * (1.f / 1024.f) - mu2 * mu2 + 1e-5f);
  float4 g2v = ((const float4*)g2)[tid], b2v = ((const float4*)b2)[tid];
  bf16* op = fln + (size_t)row * 1024 + tid * 4;
  op[0] = __float2bfloat16((h0 - mu2) * rs2 * g2v.x + b2v.x);
  op[1] = __float2bfloat16((h1 - mu2) * rs2 * g2v.y + b2v.y);
  op[2] = __float2bfloat16((h2 - mu2) * rs2 * g2v.z + b2v.z);
  op[3] = __float2bfloat16((h3 - mu2) * rs2 * g2v.w + b2v.w);
}

// ---------------- final combine: out = P0 + P1 ----------------
__global__ __launch_bounds__(256)
void add2_kernel(const float* __restrict__ a, const float* __restrict__ b,
                 float* __restrict__ o) {
  int i = blockIdx.x * 256 + threadIdx.x;
  float4 va = ((const float4*)a)[i];
  float4 vb = ((const float4*)b)[i];
  float4 vo; vo.x = va.x + vb.x; vo.y = va.y + vb.y;
  vo.z = va.z + vb.z; vo.w = va.w + vb.w;
  ((float4*)o)[i] = vo;
}

// ---------------- host launch ----------------
extern "C" void kernel_launch(void* const* d_in, const int* in_sizes, int n_in,
                              void* d_out, int out_size, void* d_ws, size_t ws_size,
                              hipStream_t stream) {
  const float* x    = (const float*)d_in[0];
  const float* adj  = (const float*)d_in[1];
  const float* Wq   = (const float*)d_in[2];
  const float* Wk   = (const float*)d_in[3];
  const float* Wv   = (const float*)d_in[4];
  const float* Wo   = (const float*)d_in[5];
  const float* Wob  = (const float*)d_in[6];
  const float* adjb = (const float*)d_in[7];
  const float* g1   = (const float*)d_in[8];
  const float* b1   = (const float*)d_in[9];
  const float* g2   = (const float*)d_in[10];
  const float* b2   = (const float*)d_in[11];
  const float* W1   = (const float*)d_in[12];
  const float* fb1  = (const float*)d_in[13];
  const float* W2   = (const float*)d_in[14];
  const float* fb2  = (const float*)d_in[15];
  float* out = (float*)d_out;

  char* w = (char*)d_ws;
  size_t off = 0;
  auto take = [&](size_t bytes) {
    char* p = w + off;
    off += (bytes + 255) & ~(size_t)255;
    return p;
  };
  bf16* xb    = (bf16*)take(4096ull * 1024 * 2);
  bf16* Wqkvt = (bf16*)take(3072ull * 1024 * 2);
  bf16* Wot   = (bf16*)take(1024ull * 1024 * 2);
  bf16* W1t   = (bf16*)take(2048ull * 1024 * 2);
  bf16* W2t   = (bf16*)take(1024ull * 2048 * 2);
  bf16* QKV   = (bf16*)take(4096ull * 3072 * 2);
  bf16* Vt    = (bf16*)take(1024ull * 4096 * 2);
  bf16* AO    = (bf16*)take(4096ull * 1024 * 2);
  u64*  adjbits = (u64*)take(4096ull * 64 * 8);
  float* lpart  = (float*)take(4ull * 4096 * 8 * 4);
  // 32MB region reused over time: AOpart -> Wo partials -> FFN2 partials
  char* big = take(32ull << 20);
  bf16*  AOpart = (bf16*)big;                       // 4 x 8MB bf16
  float* WoP    = (float*)big;                      // 2 x 16MB f32
  float* F2P    = (float*)big;                      // 2 x 16MB f32
  float* H   = (float*)take(4096ull * 1024 * 4);
  bf16*  FLN = (bf16*)take(4096ull * 1024 * 2);
  bf16*  G   = (bf16*)take(4096ull * 2048 * 2);

  dim3 tb(32, 8);
  // fused: x cvt + adj bits + all weight transposes (12288 blocks total)
  prep_all<<<12288, 256, 0, stream>>>(x, xb, adj, adjbits, Wq, Wk, Wv, Wo, W1, W2,
                                      Wqkvt, Wot, W1t, W2t);
  // QKV = xb @ [Wq|Wk|Wv]   (bf16 out)
  gemm_bt<0><<<dim3(24, 32, 1), 256, 0, stream>>>(xb, Wqkvt, nullptr, nullptr,
                                                  nullptr, QKV, 4096, 3072, 1024);
  // plain V^T per head: Vt[h*128+dh][n]
  tr_bf16t<<<dim3(32, 128), tb, 0, stream>>>(QKV + 2048, Vt, 3072);
  // flash attention, split-K x4
  attn_kernel<<<dim3(32, 8, 4), 256, 0, stream>>>(QKV, Vt, adjbits, adjb, AOpart, lpart);
  attn_norm<<<4096, 256, 0, stream>>>(AOpart, lpart, AO);
  // Wo projection, split-K x2 -> two f32 partials (z0 carries bias)
  gemm_bt<4><<<dim3(8, 32, 2), 256, 0, stream>>>(AO, Wot, Wob, nullptr,
                                                 WoP, nullptr, 4096, 1024, 1024);
  // h = LN(x + WoP0 + WoP1); FLN = bf16(LN(h))
  ln2_kernel<<<4096, 256, 0, stream>>>(x, WoP, WoP + 4096ull * 1024, g1, b1, g2, b2, H, FLN);
  // G = gelu(FLN @ W1 + b1)   (bf16 out)
  gemm_bt<2><<<dim3(16, 32, 1), 256, 0, stream>>>(FLN, W1t, fb1, nullptr,
                                                  nullptr, G, 4096, 2048, 1024);
  // FFN2 split-K x2: z0 = G@W2[:1024] + b2 ; z1 = G@W2[1024:] + h
  gemm_bt<4><<<dim3(8, 32, 2), 256, 0, stream>>>(G, W2t, fb2, H,
                                                 F2P, nullptr, 4096, 1024, 2048);
  // out = P0 + P1
  add2_kernel<<<4096, 256, 0, stream>>>(F2P, F2P + 4096ull * 1024, out);
}

// Round 13
// 434.241 us; speedup vs baseline: 1.0265x; 1.0265x over previous
//
#include <hip/hip_runtime.h>
#include <hip/hip_bf16.h>
#include <cstdint>
#include <cstddef>

typedef __hip_bfloat16 bf16;
typedef __attribute__((ext_vector_type(8))) short short8;
typedef __attribute__((ext_vector_type(4))) short short4v;
typedef __attribute__((ext_vector_type(4))) float floatx4;
typedef unsigned long long u64;

#define DEVI static __device__ __forceinline__

DEVI void load_lds16(const void* g, void* l) {
  __builtin_amdgcn_global_load_lds((const __attribute__((address_space(1))) unsigned int*)g,
                                   (__attribute__((address_space(3))) unsigned int*)l, 16, 0, 0);
}
DEVI short8 ld8(const bf16* p) { return *(const short8*)p; }
DEVI floatx4 mfma16(short8 a, short8 b, floatx4 c) {
  return __builtin_amdgcn_mfma_f32_16x16x32_bf16(a, b, c, 0, 0, 0);
}
DEVI floatx4 mfma1k(short4v a, short4v b, floatx4 c) {
  return __builtin_amdgcn_mfma_f32_16x16x16bf16_1k(a, b, c, 0, 0, 0);
}
DEVI short bfb(float f) { bf16 h = __float2bfloat16(f); return __builtin_bit_cast(short, h); }
DEVI float fbf(short s) { bf16 h = __builtin_bit_cast(bf16, s); return __bfloat162float(h); }

// ---------------- fused prep: x->bf16 + adj bits + all 6 weight transposes ----------------
// Block budget: 4096 (x/adj) + 4096 (Wq,Wk,Wv,Wo) + 2048 (W1) + 2048 (W2) = 12288.
DEVI void tr_tile(const float* in, bf16* out, int R, int C, int bx, int by) {
  __shared__ float t[32][33];
  int c0 = bx * 32, r0 = by * 32;
  int tx = threadIdx.x & 31, ty = threadIdx.x >> 5;
#pragma unroll
  for (int i = 0; i < 32; i += 8) t[ty + i][tx] = in[(size_t)(r0 + ty + i) * C + c0 + tx];
  __syncthreads();
#pragma unroll
  for (int i = 0; i < 32; i += 8)
    out[(size_t)(c0 + ty + i) * R + r0 + tx] = __float2bfloat16(t[tx][ty + i]);
}

__global__ __launch_bounds__(256)
void prep_all(const float* __restrict__ x, bf16* __restrict__ xb,
              const float* __restrict__ adj, u64* __restrict__ bits,
              const float* Wq, const float* Wk, const float* Wv, const float* Wo,
              const float* W1, const float* W2,
              bf16* Wqkvt, bf16* Wot, bf16* W1t, bf16* W2t) {
  int id = blockIdx.x;
  if (id < 4096) {
    const int row = id, tid = threadIdx.x;
    const int wave = tid >> 6, lane = tid & 63;
    float4 v = ((const float4*)(x + (size_t)row * 1024))[tid];
    bf16* o = xb + (size_t)row * 1024 + tid * 4;
    o[0] = __float2bfloat16(v.x); o[1] = __float2bfloat16(v.y);
    o[2] = __float2bfloat16(v.z); o[3] = __float2bfloat16(v.w);
    const float* arow = adj + (size_t)row * 4096;
#pragma unroll
    for (int it = 0; it < 16; it++) {
      int col = it * 256 + tid;
      u64 m = __ballot(arow[col] != 0.f);
      if (lane == 0) bits[(size_t)row * 64 + it * 4 + wave] = m;
    }
  } else if (id < 8192) {
    int q = id - 4096, w = q >> 10, t = q & 1023;
    const float* in = w == 0 ? Wq : w == 1 ? Wk : w == 2 ? Wv : Wo;
    bf16* out = w == 0 ? Wqkvt : w == 1 ? Wqkvt + 1024ull * 1024
              : w == 2 ? Wqkvt + 2048ull * 1024 : Wot;
    tr_tile(in, out, 1024, 1024, t & 31, t >> 5);
  } else if (id < 10240) {
    int t = id - 8192;
    tr_tile(W1, W1t, 1024, 2048, t & 63, t >> 6);
  } else {
    int t = id - 10240;
    tr_tile(W2, W2t, 2048, 1024, t & 31, t >> 5);
  }
}

// ---------------- plain V^T build: out[dh][n] = V[n][dh] ----------------
__global__ __launch_bounds__(256)
void tr_bf16t(const bf16* __restrict__ in, bf16* __restrict__ out, int inLd) {
  __shared__ bf16 t[32][33];
  int c0 = blockIdx.x * 32, r0 = blockIdx.y * 32;
  int tx = threadIdx.x, ty = threadIdx.y;
#pragma unroll
  for (int i = 0; i < 32; i += 8) t[ty + i][tx] = in[(size_t)(r0 + ty + i) * inLd + c0 + tx];
  __syncthreads();
#pragma unroll
  for (int i = 0; i < 32; i += 8)
    out[(size_t)(c0 + ty + i) * 4096 + r0 + tx] = t[tx][ty + i];
}

// ---------------- bf16 GEMM, C = A[M][K] @ Bt[N][K]^T, tile 128 x BN ----------------
// Pipelined K-loop: 3 LDS buffers, loads 2 tiles in flight, raw s_barrier with
// fine-grained vmcnt (never vmcnt(0) mid-loop).
// MODE 0: bf16 C (QKV) | MODE 2: bf16 gelu(C+bias) (FFN1)
// MODE 1: f32 C + bias (Wo, BN=64) | MODE 3: f32 C + bias + resid (FFN2, BN=64)
template <int MODE, int BN>
__global__ __launch_bounds__(256)
void gemm_bt(const bf16* __restrict__ A, const bf16* __restrict__ Bt,
             const float* __restrict__ bias, const float* __restrict__ resid,
             float* __restrict__ outF, bf16* __restrict__ outB,
             int M, int Nn, int K) {
  constexpr int NI = BN / 32;          // mfma col-tiles per wave
  __shared__ alignas(16) bf16 As[3][128 * 32];
  __shared__ alignas(16) bf16 Bs[3][BN * 32];
  const int tid = threadIdx.x;
  const int wave = tid >> 6, lane = tid & 63;
  const int m0 = blockIdx.y * 128, n0 = blockIdx.x * BN;
  const int wr = (wave >> 1) * 64, wc = (wave & 1) * (BN / 2);
  const int l15 = lane & 15, qq = lane >> 4;
  const int lr = lane >> 2, l4 = lane & 3;
  const int T = K >> 5;

  floatx4 acc[4][NI];
#pragma unroll
  for (int i = 0; i < 4; i++)
#pragma unroll
    for (int j = 0; j < NI; j++) acc[i][j] = (floatx4)0.f;

  const bf16* gA0 = A + (size_t)(m0 + wave * 16 + lr) * K + l4 * 8;
  const bf16* gA1 = gA0 + (size_t)64 * K;
  const bf16* gB0 = Bt + (size_t)(n0 + wave * 16 + lr) * K + l4 * 8;
  const bf16* gB1 = gB0 + (size_t)64 * K;
  const int lo = wave * 16 * 32;

  auto stage = [&](int t, int buf) {
    int kt = t * 32;
    load_lds16(gA0 + kt, &As[buf][lo]);
    load_lds16(gA1 + kt, &As[buf][64 * 32 + lo]);
    load_lds16(gB0 + kt, &Bs[buf][lo]);
    if (BN == 128) load_lds16(gB1 + kt, &Bs[buf][64 * 32 + lo]);
  };
  stage(0, 0);
  stage(1, 1);

  int bc = 0;
  for (int t = 0; t < T; ++t) {
    if (t < T - 1) {
      if constexpr (BN == 128)
        asm volatile("s_waitcnt vmcnt(4) lgkmcnt(0)" ::: "memory");
      else
        asm volatile("s_waitcnt vmcnt(3) lgkmcnt(0)" ::: "memory");
    } else {
      asm volatile("s_waitcnt vmcnt(0) lgkmcnt(0)" ::: "memory");
    }
    __builtin_amdgcn_s_barrier();
    if (t + 2 < T) { int bs = bc == 0 ? 2 : bc - 1; stage(t + 2, bs); }

    short8 af[4], bfr[NI];
#pragma unroll
    for (int mi = 0; mi < 4; mi++) af[mi] = ld8(&As[bc][(wr + mi * 16 + l15) * 32 + qq * 8]);
#pragma unroll
    for (int ni = 0; ni < NI; ni++) bfr[ni] = ld8(&Bs[bc][(wc + ni * 16 + l15) * 32 + qq * 8]);
#pragma unroll
    for (int mi = 0; mi < 4; mi++)
#pragma unroll
      for (int ni = 0; ni < NI; ni++)
        acc[mi][ni] = mfma16(af[mi], bfr[ni], acc[mi][ni]);
    bc = bc == 2 ? 0 : bc + 1;
  }

#pragma unroll
  for (int mi = 0; mi < 4; mi++) {
    int row = m0 + wr + mi * 16 + qq * 4;
#pragma unroll
    for (int ni = 0; ni < NI; ni++) {
      int col = n0 + wc + ni * 16 + l15;
      float bv = (MODE >= 1) ? bias[col] : 0.f;
#pragma unroll
      for (int r = 0; r < 4; r++) {
        float v = acc[mi][ni][r] + bv;
        size_t off = (size_t)(row + r) * Nn + col;
        if (MODE == 0) {
          outB[off] = __float2bfloat16(v);
        } else if (MODE == 2) {
          outB[off] = __float2bfloat16(0.5f * v * (1.f + erff(v * 0.70710678118654752f)));
        } else if (MODE == 1) {
          outF[off] = v;
        } else {
          outF[off] = v + resid[off];
        }
      }
    }
  }
}

// ---------------- flash attention v13 (= R11): transposed-S, register P, async staging ---
// grid (32 q-tiles, 8 heads, 4 splits); 256 thr; LDS 32KB.
// S^T = K·Q^T (C-layout = A-operand layout of 16x16x16 mfma) -> P stays in registers.
__global__ __launch_bounds__(256, 2)
void attn_kernel(const bf16* __restrict__ QKV, const bf16* __restrict__ Vt,
                 const u64* __restrict__ adjbits, const float* __restrict__ adj_bias,
                 bf16* __restrict__ AOpart, float* __restrict__ lpart) {
  __shared__ alignas(16) bf16 Kf[16 * 512];  // frag fi=ni*4+kk: K[kt+ni*16+l15][kk*32+qq*8+..]
  __shared__ alignas(16) bf16 Vf[16 * 512];  // frag fi=d*2+k2:  V^T[d*16+l15][kt+k2*32+qq*8+..]
  const int q0 = blockIdx.x * 128;
  const int h = blockIdx.y;
  const int split = blockIdx.z;
  const int k0 = split * 1024;
  const int tid = threadIdx.x, wave = tid >> 6, lane = tid & 63;
  const int l15 = lane & 15, qq = lane >> 4;
  const float beta = adj_bias[h];
  const float scale = 0.08838834764831845f;  // 128^-0.5

  // Q fragments (B-operand; 32 rows per wave)
  short8 qf[2][4];
#pragma unroll
  for (int mi = 0; mi < 2; mi++)
#pragma unroll
    for (int kk = 0; kk < 4; kk++)
      qf[mi][kk] = ld8(&QKV[(size_t)(q0 + wave * 32 + mi * 16 + l15) * 3072 +
                            h * 128 + kk * 32 + qq * 8]);

  floatx4 o[2][8];
#pragma unroll
  for (int mi = 0; mi < 2; mi++)
#pragma unroll
    for (int d = 0; d < 8; d++) o[mi][d] = (floatx4)0.f;
  float lrow[2] = {0.f, 0.f};

  const size_t abase = (size_t)(q0 + wave * 32 + l15) * 64 + split * 16;

  for (int t = 0; t < 16; t++) {
    const int kt = k0 + t * 64;
    __syncthreads();  // all waves done reading Kf/Vf from prev iter
#pragma unroll
    for (int i = 0; i < 4; i++) {
      int fi = wave * 4 + i;
      int ni = fi >> 2, kk = fi & 3;
      load_lds16(&QKV[(size_t)(kt + ni * 16 + l15) * 3072 + 1024 + h * 128 + kk * 32 + qq * 8],
                 (char*)Kf + fi * 1024);
      int d = fi >> 1, k2 = fi & 1;
      load_lds16(&Vt[(size_t)(h * 128 + d * 16 + l15) * 4096 + kt + k2 * 32 + qq * 8],
                 (char*)Vf + fi * 1024);
    }
    // adj words (broadcast within quads; overlapped with staging)
    u64 ab0 = adjbits[abase + t];
    u64 ab1 = adjbits[abase + 1024 + t];
    asm volatile("s_waitcnt vmcnt(0)" ::: "memory");
    __syncthreads();  // staged & visible

    // per 16-key step: S^T -> softmax -> PV (P never touches LDS)
#pragma unroll
    for (int ni = 0; ni < 4; ni++) {
      floatx4 s0 = (floatx4)0.f, s1 = (floatx4)0.f;
#pragma unroll
      for (int kk = 0; kk < 4; kk++) {
        short8 kf = ld8(&Kf[(ni * 4 + kk) * 512 + lane * 8]);
        s0 = mfma16(kf, qf[0][kk], s0);  // D[key][q] for q-subtile 0
        s1 = mfma16(kf, qf[1][kk], s1);
      }
      short4v pa0, pa1;
      {
        float p0, p1, p2, p3;
        int bp = ni * 16 + qq * 4;
        p0 = __expf(fmaf(s0[0], scale, ((ab0 >> (bp + 0)) & 1) ? beta : 0.f));
        p1 = __expf(fmaf(s0[1], scale, ((ab0 >> (bp + 1)) & 1) ? beta : 0.f));
        p2 = __expf(fmaf(s0[2], scale, ((ab0 >> (bp + 2)) & 1) ? beta : 0.f));
        p3 = __expf(fmaf(s0[3], scale, ((ab0 >> (bp + 3)) & 1) ? beta : 0.f));
        lrow[0] += (p0 + p1) + (p2 + p3);
        pa0.x = bfb(p0); pa0.y = bfb(p1); pa0.z = bfb(p2); pa0.w = bfb(p3);
        p0 = __expf(fmaf(s1[0], scale, ((ab1 >> (bp + 0)) & 1) ? beta : 0.f));
        p1 = __expf(fmaf(s1[1], scale, ((ab1 >> (bp + 1)) & 1) ? beta : 0.f));
        p2 = __expf(fmaf(s1[2], scale, ((ab1 >> (bp + 2)) & 1) ? beta : 0.f));
        p3 = __expf(fmaf(s1[3], scale, ((ab1 >> (bp + 3)) & 1) ? beta : 0.f));
        lrow[1] += (p0 + p1) + (p2 + p3);
        pa1.x = bfb(p0); pa1.y = bfb(p1); pa1.z = bfb(p2); pa1.w = bfb(p3);
      }
      // PV: B-frag = V^T[d*16+l15][kt+ni*16+qq*4 .. +3] from Vf (b64)
      const int voff = ((ni & 1) * 2 + (qq >> 1)) * 256 + l15 * 16 + (qq & 1) * 8;
#pragma unroll
      for (int d = 0; d < 8; d++) {
        short4v vf = *(const short4v*)((const char*)Vf + (d * 2 + (ni >> 1)) * 1024 + voff);
        o[0][d] = mfma1k(pa0, vf, o[0][d]);
        o[1][d] = mfma1k(pa1, vf, o[1][d]);
      }
    }
  }

  // epilogue: reduce lrow over quads; write bf16 partials (additive across splits)
#pragma unroll
  for (int mi = 0; mi < 2; mi++) {
    float v = lrow[mi];
    v += __shfl_xor(v, 16, 64);
    v += __shfl_xor(v, 32, 64);
    if (qq == 0) lpart[((size_t)split * 4096 + q0 + wave * 32 + mi * 16 + l15) * 8 + h] = v;
#pragma unroll
    for (int r = 0; r < 4; r++) {
      int grow = q0 + wave * 32 + mi * 16 + qq * 4 + r;
      bf16* dst = AOpart + ((size_t)split * 4096 + grow) * 1024 + h * 128;
#pragma unroll
      for (int d = 0; d < 8; d++) dst[d * 16 + l15] = __float2bfloat16(o[mi][d][r]);
    }
  }
}

// ---------------- combine split-K partials, normalize -> bf16 AO ----------------
__global__ __launch_bounds__(256)
void attn_norm(const bf16* __restrict__ AOpart, const float* __restrict__ lpart,
               bf16* __restrict__ AO) {
  int row = blockIdx.x, tid = threadIdx.x;
  int h = tid >> 5;
  float ls = 0.f;
#pragma unroll
  for (int s = 0; s < 4; s++) ls += lpart[((size_t)s * 4096 + row) * 8 + h];
  float a0 = 0.f, a1 = 0.f, a2 = 0.f, a3 = 0.f;
#pragma unroll
  for (int s = 0; s < 4; s++) {
    short4v v = *(const short4v*)&AOpart[((size_t)s * 4096 + row) * 1024 + tid * 4];
    a0 += fbf(v.x); a1 += fbf(v.y); a2 += fbf(v.z); a3 += fbf(v.w);
  }
  float inv = 1.f / ls;
  bf16* op = AO + (size_t)row * 1024 + tid * 4;
  op[0] = __float2bfloat16(a0 * inv);
  op[1] = __float2bfloat16(a1 * inv);
  op[2] = __float2bfloat16(a2 * inv);
  op[3] = __float2bfloat16(a3 * inv);
}

// ---------------- fused double-LayerNorm ----------------
DEVI void block_sum2(float& a, float& b, float* red) {
#pragma unroll
  for (int o = 1; o < 64; o <<= 1) { a += __shfl_xor(a, o, 64); b += __shfl_xor(b, o, 64); }
  int wv = threadIdx.x >> 6;
  if ((threadIdx.x & 63) == 0) { red[wv] = a; red[4 + wv] = b; }
  __syncthreads();
  a = red[0] + red[1] + red[2] + red[3];
  b = red[4] + red[5] + red[6] + red[7];
  __syncthreads();
}

__global__ __launch_bounds__(256)
void ln2_kernel(const float* __restrict__ x, const float* __restrict__ ao,
                const float* __restrict__ g1, const float* __restrict__ b1,
                const float* __restrict__ g2, const float* __restrict__ b2,
                float* __restrict__ hout, bf16* __restrict__ fln) {
  __shared__ float red[8];
  const int row = blockIdx.x, tid = threadIdx.x;
  float4 xv = ((const float4*)(x + (size_t)row * 1024))[tid];
  float4 av = ((const float4*)(ao + (size_t)row * 1024))[tid];
  float s0 = xv.x + av.x, s1 = xv.y + av.y, s2 = xv.z + av.z, s3 = xv.w + av.w;
  float sum = s0 + s1 + s2 + s3;
  float ssq = s0 * s0 + s1 * s1 + s2 * s2 + s3 * s3;
  block_sum2(sum, ssq, red);
  float mu = sum * (1.f / 1024.f);
  float rs = rsqrtf(ssq * (1.f / 1024.f) - mu * mu + 1e-5f);
  float4 gv = ((const float4*)g1)[tid], bv = ((const float4*)b1)[tid];
  float h0 = (s0 - mu) * rs * gv.x + bv.x;
  float h1 = (s1 - mu) * rs * gv.y + bv.y;
  float h2 = (s2 - mu) * rs * gv.z + bv.z;
  float h3 = (s3 - mu) * rs * gv.w + bv.w;
  float4 hv; hv.x = h0; hv.y = h1; hv.z = h2; hv.w = h3;
  ((float4*)(hout + (size_t)row * 1024))[tid] = hv;
  float sum2 = h0 + h1 + h2 + h3;
  float ssq2 = h0 * h0 + h1 * h1 + h2 * h2 + h3 * h3;
  block_sum2(sum2, ssq2, red);
  float mu2 = sum2 * (1.f / 1024.f);
  float rs2 = rsqrtf(ssq2 * (1.f / 1024.f) - mu2 * mu2 + 1e-5f);
  float4 g2v = ((const float4*)g2)[tid], b2v = ((const float4*)b2)[tid];
  bf16* op = fln + (size_t)row * 1024 + tid * 4;
  op[0] = __float2bfloat16((h0 - mu2) * rs2 * g2v.x + b2v.x);
  op[1] = __float2bfloat16((h1 - mu2) * rs2 * g2v.y + b2v.y);
  op[2] = __float2bfloat16((h2 - mu2) * rs2 * g2v.z + b2v.z);
  op[3] = __float2bfloat16((h3 - mu2) * rs2 * g2v.w + b2v.w);
}

// ---------------- host launch ----------------
extern "C" void kernel_launch(void* const* d_in, const int* in_sizes, int n_in,
                              void* d_out, int out_size, void* d_ws, size_t ws_size,
                              hipStream_t stream) {
  const float* x    = (const float*)d_in[0];
  const float* adj  = (const float*)d_in[1];
  const float* Wq   = (const float*)d_in[2];
  const float* Wk   = (const float*)d_in[3];
  const float* Wv   = (const float*)d_in[4];
  const float* Wo   = (const float*)d_in[5];
  const float* Wob  = (const float*)d_in[6];
  const float* adjb = (const float*)d_in[7];
  const float* g1   = (const float*)d_in[8];
  const float* b1   = (const float*)d_in[9];
  const float* g2   = (const float*)d_in[10];
  const float* b2   = (const float*)d_in[11];
  const float* W1   = (const float*)d_in[12];
  const float* fb1  = (const float*)d_in[13];
  const float* W2   = (const float*)d_in[14];
  const float* fb2  = (const float*)d_in[15];
  float* out = (float*)d_out;

  char* w = (char*)d_ws;
  size_t off = 0;
  auto take = [&](size_t bytes) {
    char* p = w + off;
    off += (bytes + 255) & ~(size_t)255;
    return p;
  };
  bf16* xb    = (bf16*)take(4096ull * 1024 * 2);
  bf16* Wqkvt = (bf16*)take(3072ull * 1024 * 2);
  bf16* Wot   = (bf16*)take(1024ull * 1024 * 2);
  bf16* W1t   = (bf16*)take(2048ull * 1024 * 2);
  bf16* W2t   = (bf16*)take(1024ull * 2048 * 2);
  bf16* QKV   = (bf16*)take(4096ull * 3072 * 2);
  bf16* Vt    = (bf16*)take(1024ull * 4096 * 2);
  bf16* AO    = (bf16*)take(4096ull * 1024 * 2);
  u64*  adjbits = (u64*)take(4096ull * 64 * 8);
  float* lpart  = (float*)take(4ull * 4096 * 8 * 4);
  // 32MB region reused over time: AOpart (until attn_norm) -> WoP (after)
  char* big = take(32ull << 20);
  bf16*  AOpart = (bf16*)big;                       // 4 x 8MB bf16
  float* WoP    = (float*)big;                      // 16MB f32
  float* H   = (float*)take(4096ull * 1024 * 4);
  bf16*  FLN = (bf16*)take(4096ull * 1024 * 2);
  bf16*  G   = (bf16*)take(4096ull * 2048 * 2);

  dim3 tb(32, 8);
  // fused: x cvt + adj bits + all weight transposes (12288 blocks total)
  prep_all<<<12288, 256, 0, stream>>>(x, xb, adj, adjbits, Wq, Wk, Wv, Wo, W1, W2,
                                      Wqkvt, Wot, W1t, W2t);
  // QKV = xb @ [Wq|Wk|Wv]   (bf16 out)
  gemm_bt<0, 128><<<dim3(24, 32), 256, 0, stream>>>(xb, Wqkvt, nullptr, nullptr,
                                                    nullptr, QKV, 4096, 3072, 1024);
  // plain V^T per head: Vt[h*128+dh][n]
  tr_bf16t<<<dim3(32, 128), tb, 0, stream>>>(QKV + 2048, Vt, 3072);
  // flash attention, split-K x4
  attn_kernel<<<dim3(32, 8, 4), 256, 0, stream>>>(QKV, Vt, adjbits, adjb, AOpart, lpart);
  attn_norm<<<4096, 256, 0, stream>>>(AOpart, lpart, AO);
  // WoP = AO @ Wo + Wo_b   (f32 out; 128x64 tiles -> 512 blocks, no split-K)
  gemm_bt<1, 64><<<dim3(16, 32), 256, 0, stream>>>(AO, Wot, Wob, nullptr,
                                                   WoP, nullptr, 4096, 1024, 1024);
  // h = LN(x + WoP); FLN = bf16(LN(h))
  ln2_kernel<<<4096, 256, 0, stream>>>(x, WoP, g1, b1, g2, b2, H, FLN);
  // G = gelu(FLN @ W1 + b1)   (bf16 out)
  gemm_bt<2, 128><<<dim3(16, 32), 256, 0, stream>>>(FLN, W1t, fb1, nullptr,
                                                    nullptr, G, 4096, 2048, 1024);
  // out = G @ W2 + b2 + h   (f32 out; 128x64 tiles -> 512 blocks, no split-K)
  gemm_bt<3, 64><<<dim3(16, 32), 256, 0, stream>>>(G, W2t, fb2, H,
                                                   out, nullptr, 4096, 1024, 2048);
}